// Round 1
// baseline (956.955 us; speedup 1.0000x reference)
//
#include <hip/hip_runtime.h>

// Symmetric pair-weight recurrent net, T=8192 units, 8 propagation steps.
// M is symmetric with zero diagonal, stored as strict upper triangle row-major:
//   w(i,j) = w_flat[off(i) + (j - i - 1)],  off(i) = i*(T-1) - i*(i-1)/2
// Each iteration: y = M @ s  (each pair used twice), s = tanh(y + b).

constexpr int T      = 8192;
constexpr int IN     = 2048;
constexpr int OUT    = 1024;
constexpr int NPROP  = 8;
constexpr int TILE   = 128;
constexpr int NT     = T / TILE;              // 64
constexpr int NTILES = NT * (NT + 1) / 2;     // 2080 upper-triangular tiles

__global__ __launch_bounds__(256) void init_kernel(const float* __restrict__ in,
                                                   float* __restrict__ s,
                                                   float* __restrict__ y) {
    int n = blockIdx.x * 256 + threadIdx.x;
    if (n < T) {
        s[n] = (n < IN) ? in[n] : 0.0f;
        y[n] = 0.0f;
    }
}

__global__ __launch_bounds__(256) void accum_kernel(const float* __restrict__ w,
                                                    const float* __restrict__ s,
                                                    float* __restrict__ y) {
    __shared__ float sI[TILE], sJ[TILE];

    // Map linear block id -> (bi, bj) with bi <= bj (upper-triangular tiles).
    unsigned p = blockIdx.x;
    unsigned bi = 0, rem = p;
    while (rem >= (unsigned)(NT - (int)bi)) { rem -= (NT - bi); ++bi; }
    unsigned bj = bi + rem;
    unsigned i0 = bi * TILE, j0 = bj * TILE;

    int t = threadIdx.x;
    if (t < TILE) { sI[t] = s[i0 + t]; sJ[t] = s[j0 + t]; }
    __syncthreads();

    bool diag = (bi == bj);
    int wave = t >> 6, lane = t & 63;

    // ---- Phase 1: y[i] += sum_j w(i,j) * s[j]  (row dot, wave per row) ----
    for (int ii = wave; ii < TILE; ii += 4) {
        unsigned i = i0 + (unsigned)ii;
        // base + jj indexes w(i, j0+jj); unsigned wrap is exact for valid jj
        unsigned base = i * (unsigned)(T - 1) - ((i * (i - 1)) >> 1) + (j0 - i - 1u);
        float sum = 0.0f;
        int ja = lane, jb = lane + 64;
        if (!diag || ja > ii) sum += w[base + (unsigned)ja] * sJ[ja];
        if (!diag || jb > ii) sum += w[base + (unsigned)jb] * sJ[jb];
        #pragma unroll
        for (int o = 32; o > 0; o >>= 1) sum += __shfl_xor(sum, o, 64);
        if (lane == 0) atomicAdd(&y[i], sum);
    }

    // ---- Phase 2: y[j] += sum_i w(i,j) * s[i]  (column accumulate) ----
    {
        int jj = t & (TILE - 1);
        int h  = t >> 7;   // which half of the rows this thread covers
        float acc = 0.0f;
        #pragma unroll 4
        for (int k = 0; k < TILE / 2; ++k) {
            int ii = h * (TILE / 2) + k;
            unsigned i = i0 + (unsigned)ii;
            unsigned base = i * (unsigned)(T - 1) - ((i * (i - 1)) >> 1) + (j0 - i - 1u);
            if (!diag || jj > ii) acc += w[base + (unsigned)jj] * sI[ii];
        }
        atomicAdd(&y[j0 + (unsigned)jj], acc);
    }
}

__global__ __launch_bounds__(256) void act_kernel(const float* __restrict__ b,
                                                  float* __restrict__ s,
                                                  float* __restrict__ y) {
    int n = blockIdx.x * 256 + threadIdx.x;
    if (n < T) {
        s[n] = tanhf(y[n] + b[n]);
        y[n] = 0.0f;   // re-zero accumulator for the next iteration
    }
}

__global__ __launch_bounds__(256) void out_kernel(const float* __restrict__ s,
                                                  float* __restrict__ o) {
    int n = blockIdx.x * 256 + threadIdx.x;
    if (n < OUT) o[n] = s[T - OUT + n];
}

extern "C" void kernel_launch(void* const* d_in, const int* in_sizes, int n_in,
                              void* d_out, int out_size, void* d_ws, size_t ws_size,
                              hipStream_t stream) {
    const float* in = (const float*)d_in[0];   // inputs [2048]
    const float* w  = (const float*)d_in[1];   // w_flat [T*(T-1)/2]
    const float* b  = (const float*)d_in[2];   // b [8192]
    float* out = (float*)d_out;                // [1024] f32

    // Workspace layout: s [T] f32, y [T] f32  (64 KB total)
    float* s = (float*)d_ws;
    float* y = s + T;

    init_kernel<<<(T + 255) / 256, 256, 0, stream>>>(in, s, y);
    for (int it = 0; it < NPROP; ++it) {
        accum_kernel<<<NTILES, 256, 0, stream>>>(w, s, y);
        act_kernel<<<(T + 255) / 256, 256, 0, stream>>>(b, s, y);
    }
    out_kernel<<<(OUT + 255) / 256, 256, 0, stream>>>(s, out);
}

// Round 2
// 429.088 us; speedup vs baseline: 2.2302x; 2.2302x over previous
//
#include <hip/hip_runtime.h>

// Symmetric pair-weight recurrent net, T=8192 units, 8 propagation steps.
// M symmetric, zero diagonal, strict upper triangle row-major:
//   w(i,j) = w_flat[off(i) + (j - i - 1)],  off(i) = i*(T-1) - i*(i-1)/2
// Per iteration: y = M @ s, s = tanh(y + b).
// Single-pass tiles: each weight element read ONCE, contributing to
// y[i] (+= w * s[j], wave shfl-reduce) and y[j] (+= w * s[i], register acc).

constexpr int T      = 8192;
constexpr int IN     = 2048;
constexpr int OUT    = 1024;
constexpr int NPROP  = 8;
constexpr int TILE   = 128;
constexpr int NT     = T / TILE;              // 64
constexpr int NTILES = NT * (NT + 1) / 2;     // 2080 upper-triangular tiles

__global__ __launch_bounds__(256) void init_kernel(const float* __restrict__ in,
                                                   float* __restrict__ s,
                                                   float* __restrict__ y) {
    int n = blockIdx.x * 256 + threadIdx.x;
    if (n < T) {
        s[n] = (n < IN) ? in[n] : 0.0f;
        y[n] = 0.0f;
    }
}

__device__ __forceinline__ unsigned rowstart(int b) {
    return (unsigned)(b * NT) - (unsigned)((b * (b - 1)) >> 1);
}

__global__ __launch_bounds__(256) void accum_kernel(const float* __restrict__ w,
                                                    const float* __restrict__ s,
                                                    float* __restrict__ y) {
    __shared__ float sI[TILE], sJ[TILE];
    __shared__ float colpart[4][TILE];

    // Closed-form linear block id -> (bi, bj), bi <= bj, with fixup.
    unsigned p = blockIdx.x;
    const float A = (float)(2 * NT + 1);      // 129
    int bi = (int)((A - sqrtf(A * A - 8.0f * (float)p)) * 0.5f);
    if (bi < 0) bi = 0;
    while (rowstart(bi + 1) <= p) ++bi;
    while (rowstart(bi) > p) --bi;
    int bj = bi + (int)(p - rowstart(bi));
    unsigned i0 = (unsigned)bi * TILE, j0 = (unsigned)bj * TILE;

    int t = threadIdx.x;
    if (t < TILE) { sI[t] = s[i0 + t]; sJ[t] = s[j0 + t]; }
    __syncthreads();

    int wv = t >> 6, lane = t & 63;
    float sj0 = sJ[lane], sj1 = sJ[lane + 64];

    int iiBase = wv * 32;                      // each wave owns 32 rows
    unsigned icur = i0 + (unsigned)iiBase;
    // base(i) = off(i) + j0 - i - 1; unsigned wrap is exact (tile 0,0 row 0
    // gives base = -1, masked lanes have lane >= 1 so addr = lane-1 >= 0).
    unsigned base = icur * (unsigned)(T - 1) - ((icur * (icur - 1u)) >> 1)
                  + j0 - icur - 1u;

    float cacc0 = 0.0f, cacc1 = 0.0f;

    if (bi != bj) {
        // ---- off-diagonal tile: branch-free inner loop ----
        #pragma unroll 8
        for (int k = 0; k < 32; ++k) {
            unsigned irow = icur + (unsigned)k;
            float w0 = w[base + (unsigned)lane];
            float w1 = w[base + (unsigned)(lane + 64)];
            float si = sI[iiBase + k];
            float rsum = w0 * sj0 + w1 * sj1;
            cacc0 = fmaf(w0, si, cacc0);
            cacc1 = fmaf(w1, si, cacc1);
            #pragma unroll
            for (int o = 32; o; o >>= 1) rsum += __shfl_xor(rsum, o, 64);
            if (lane == 0) atomicAdd(&y[irow], rsum);
            base += (unsigned)(T - 2) - irow;
        }
    } else {
        // ---- diagonal tile: strict upper (j > i) only, masked loads ----
        #pragma unroll 4
        for (int k = 0; k < 32; ++k) {
            int ii = iiBase + k;
            unsigned irow = icur + (unsigned)k;
            float w0 = (lane > ii) ? w[base + (unsigned)lane] : 0.0f;
            float w1 = (lane + 64 > ii) ? w[base + (unsigned)(lane + 64)] : 0.0f;
            float si = sI[ii];
            float rsum = w0 * sj0 + w1 * sj1;
            cacc0 = fmaf(w0, si, cacc0);
            cacc1 = fmaf(w1, si, cacc1);
            #pragma unroll
            for (int o = 32; o; o >>= 1) rsum += __shfl_xor(rsum, o, 64);
            if (lane == 0) atomicAdd(&y[irow], rsum);
            base += (unsigned)(T - 2) - irow;
        }
    }

    // ---- column partial reduction across the 4 waves ----
    colpart[wv][lane]      = cacc0;
    colpart[wv][lane + 64] = cacc1;
    __syncthreads();
    if (t < TILE) {
        float c = colpart[0][t] + colpart[1][t] + colpart[2][t] + colpart[3][t];
        atomicAdd(&y[j0 + (unsigned)t], c);
    }
}

__global__ __launch_bounds__(256) void act_kernel(const float* __restrict__ b,
                                                  float* __restrict__ s,
                                                  float* __restrict__ y) {
    int n = blockIdx.x * 256 + threadIdx.x;
    if (n < T) {
        s[n] = tanhf(y[n] + b[n]);
        y[n] = 0.0f;   // re-zero accumulator for the next iteration
    }
}

__global__ __launch_bounds__(256) void out_kernel(const float* __restrict__ s,
                                                  float* __restrict__ o) {
    int n = blockIdx.x * 256 + threadIdx.x;
    if (n < OUT) o[n] = s[T - OUT + n];
}

extern "C" void kernel_launch(void* const* d_in, const int* in_sizes, int n_in,
                              void* d_out, int out_size, void* d_ws, size_t ws_size,
                              hipStream_t stream) {
    const float* in = (const float*)d_in[0];   // inputs [2048]
    const float* w  = (const float*)d_in[1];   // w_flat [T*(T-1)/2]
    const float* b  = (const float*)d_in[2];   // b [8192]
    float* out = (float*)d_out;                // [1024] f32

    float* s = (float*)d_ws;                   // [T]
    float* y = s + T;                          // [T]

    init_kernel<<<(T + 255) / 256, 256, 0, stream>>>(in, s, y);
    for (int it = 0; it < NPROP; ++it) {
        accum_kernel<<<NTILES, 256, 0, stream>>>(w, s, y);
        act_kernel<<<(T + 255) / 256, 256, 0, stream>>>(b, s, y);
    }
    out_kernel<<<(OUT + 255) / 256, 256, 0, stream>>>(s, out);
}

// Round 3
// 291.115 us; speedup vs baseline: 3.2872x; 1.4739x over previous
//
#include <hip/hip_runtime.h>
#include <hip/hip_fp16.h>

// Symmetric pair-weight recurrent net, T=8192, 8 steps of s = tanh(M s + b).
// Strategy: materialize M once as full fp16 row-major [T][T] (134 MB, fits in
// the 256 MB Infinity Cache), then 8 fused GEMV+tanh passes with coalesced
// uint4 loads. w_flat upper-tri layout: idx(i,j) = i*(T-1) - i*(i-1)/2 + j-i-1.

constexpr int T     = 8192;
constexpr int IN    = 2048;
constexpr int OUT   = 1024;
constexpr int NPROP = 8;

// --- materialization tiling: 64x64 tiles over the upper triangle ---
constexpr int MT      = 64;
constexpr int MNT     = T / MT;                  // 128
constexpr int MNTILES = MNT * (MNT + 1) / 2;     // 8256

__device__ __forceinline__ unsigned mrowstart(int bb) {
    return (unsigned)(bb * MNT) - (unsigned)((bb * (bb - 1)) >> 1);
}

__global__ __launch_bounds__(256) void mat_kernel(const float* __restrict__ w,
                                                  __half* __restrict__ M) {
    __shared__ float tl[MT][MT + 1];   // +1 pad: conflict-free transpose reads

    // linear tile id -> (bi, bj), bi <= bj
    unsigned p = blockIdx.x;
    const float A = (float)(2 * MNT + 1);   // 257
    int bi = (int)((A - sqrtf(A * A - 8.0f * (float)p)) * 0.5f);
    if (bi < 0) bi = 0;
    while (mrowstart(bi + 1) <= p) ++bi;
    while (mrowstart(bi) > p) --bi;
    int bj = bi + (int)(p - mrowstart(bi));
    unsigned i0 = (unsigned)bi * MT, j0 = (unsigned)bj * MT;

    int t = threadIdx.x;
    int c = t & 63;          // column within tile (lane)
    int rw = t >> 6;         // 0..3 (wave id -> row offset)

    if (bi != bj) {
        #pragma unroll
        for (int st = 0; st < MT; st += 4) {
            int r = st + rw;
            unsigned i = i0 + (unsigned)r;
            unsigned idx = i * (unsigned)(T - 1) - ((i * (i - 1u)) >> 1)
                         + (j0 + (unsigned)c) - i - 1u;
            float wv = w[idx];
            tl[r][c] = wv;
            M[(size_t)i * T + j0 + c] = __float2half_rn(wv);
        }
        __syncthreads();
        #pragma unroll
        for (int st = 0; st < MT; st += 4) {
            int r = st + rw;
            M[(size_t)(j0 + r) * T + i0 + c] = __float2half_rn(tl[c][r]);
        }
    } else {
        #pragma unroll
        for (int st = 0; st < MT; st += 4) {
            int r = st + rw;
            unsigned i = i0 + (unsigned)r;
            float wv = 0.0f;
            if (c > r) {
                unsigned idx = i * (unsigned)(T - 1) - ((i * (i - 1u)) >> 1)
                             + (j0 + (unsigned)c) - i - 1u;
                wv = w[idx];
            }
            tl[r][c] = wv;
        }
        __syncthreads();
        #pragma unroll
        for (int st = 0; st < MT; st += 4) {
            int r = st + rw;
            float v = (c > r) ? tl[r][c] : tl[c][r];   // c==r -> tl[r][r]==0
            M[(size_t)(i0 + r) * T + i0 + c] = __float2half_rn(v);
        }
    }
}

__global__ __launch_bounds__(256) void init_kernel(const float* __restrict__ in,
                                                   float* __restrict__ s) {
    int n = blockIdx.x * 256 + threadIdx.x;
    if (n < T) s[n] = (n < IN) ? in[n] : 0.0f;
}

// Fused y = M s ; s_out = tanh(y + b). One wave per 4 rows, 16 rows/block.
__global__ __launch_bounds__(256) void gemv_kernel(const __half* __restrict__ M,
                                                   const float* __restrict__ sin,
                                                   const float* __restrict__ b,
                                                   float* __restrict__ sout) {
    __shared__ __align__(16) float ss[T];   // 32 KB state stage
    int t = threadIdx.x;
    #pragma unroll
    for (int k = 0; k < T / 4 / 256; ++k)
        ((float4*)ss)[t + 256 * k] = ((const float4*)sin)[t + 256 * k];
    __syncthreads();

    int wv = t >> 6, lane = t & 63;
    int row = blockIdx.x * 16 + wv * 4;

    for (int rr = 0; rr < 4; ++rr, ++row) {
        const __half* mr = M + (size_t)row * T;
        float acc0 = 0.0f, acc1 = 0.0f;
        #pragma unroll 8
        for (int k = 0; k < 16; ++k) {
            int col = k * 512 + lane * 8;
            uint4 mv = *(const uint4*)(mr + col);
            float4 s0 = *(const float4*)&ss[col];
            float4 s1 = *(const float4*)&ss[col + 4];
            float2 a0 = __half22float2(*reinterpret_cast<__half2*>(&mv.x));
            float2 a1 = __half22float2(*reinterpret_cast<__half2*>(&mv.y));
            float2 a2 = __half22float2(*reinterpret_cast<__half2*>(&mv.z));
            float2 a3 = __half22float2(*reinterpret_cast<__half2*>(&mv.w));
            acc0 = fmaf(a0.x, s0.x, acc0); acc0 = fmaf(a0.y, s0.y, acc0);
            acc0 = fmaf(a1.x, s0.z, acc0); acc0 = fmaf(a1.y, s0.w, acc0);
            acc1 = fmaf(a2.x, s1.x, acc1); acc1 = fmaf(a2.y, s1.y, acc1);
            acc1 = fmaf(a3.x, s1.z, acc1); acc1 = fmaf(a3.y, s1.w, acc1);
        }
        float acc = acc0 + acc1;
        #pragma unroll
        for (int o = 32; o; o >>= 1) acc += __shfl_xor(acc, o, 64);
        if (lane == 0) sout[row] = tanhf(acc + b[row]);
    }
}

__global__ __launch_bounds__(256) void out_kernel(const float* __restrict__ s,
                                                  float* __restrict__ o) {
    int n = blockIdx.x * 256 + threadIdx.x;
    if (n < OUT) o[n] = s[T - OUT + n];
}

extern "C" void kernel_launch(void* const* d_in, const int* in_sizes, int n_in,
                              void* d_out, int out_size, void* d_ws, size_t ws_size,
                              hipStream_t stream) {
    const float* in = (const float*)d_in[0];   // inputs [2048]
    const float* w  = (const float*)d_in[1];   // w_flat [T*(T-1)/2] f32
    const float* b  = (const float*)d_in[2];   // b [8192] f32
    float* out = (float*)d_out;                // [1024] f32

    // Workspace: M fp16 [T][T] = 128 MiB, then two f32 state buffers.
    __half* M  = (__half*)d_ws;
    float*  s0 = (float*)((char*)d_ws + (size_t)T * T * sizeof(__half));
    float*  s1 = s0 + T;

    mat_kernel<<<MNTILES, 256, 0, stream>>>(w, M);
    init_kernel<<<(T + 255) / 256, 256, 0, stream>>>(in, s0);

    float* cur = s0;
    float* nxt = s1;
    for (int it = 0; it < NPROP; ++it) {
        gemv_kernel<<<T / 16, 256, 0, stream>>>(M, cur, b, nxt);
        float* tmp = cur; cur = nxt; nxt = tmp;
    }
    out_kernel<<<(OUT + 255) / 256, 256, 0, stream>>>(cur, out);
}

// Round 4
// 201.196 us; speedup vs baseline: 4.7563x; 1.4469x over previous
//
#include <hip/hip_runtime.h>
#include <hip/hip_fp16.h>

// Symmetric pair-weight recurrent net, T=8192, 8 steps of s = tanh(M s + b).
// Strategy: materialize M once as full fp16 row-major [T][T] (134 MB, lives in
// the 256 MB Infinity Cache), then 8 fused GEMV+tanh passes.
//   - mat: register-block 4x4 transpose, no LDS
//   - state kept in fp16; staged to 16 KB LDS per block (8 blocks/CU)
//   - iter 1 reads only cols < IN (rest of state is zero)
//   - iter 8 computes only the last OUT rows, writes f32 straight to d_out
// w_flat upper-tri layout: idx(i,j) = i*(T-1) - i*(i-1)/2 + j-i-1.

constexpr int T     = 8192;
constexpr int IN    = 2048;
constexpr int OUT   = 1024;
constexpr int NPROP = 8;

constexpr int MT      = 64;
constexpr int MNT     = T / MT;                  // 128
constexpr int MNTILES = MNT * (MNT + 1) / 2;     // 8256

__device__ __forceinline__ unsigned mrowstart(int bb) {
    return (unsigned)(bb * MNT) - (unsigned)((bb * (bb - 1)) >> 1);
}

__device__ __forceinline__ unsigned triidx(unsigned i, unsigned j) {
    // strict upper triangle, j > i
    return i * (unsigned)(T - 1) - ((i * (i - 1u)) >> 1) + j - i - 1u;
}

__global__ __launch_bounds__(256) void mat_kernel(const float* __restrict__ w,
                                                  __half* __restrict__ M) {
    // linear tile id -> (bi, bj), bi <= bj
    unsigned p = blockIdx.x;
    const float A = (float)(2 * MNT + 1);   // 257
    int bi = (int)((A - sqrtf(A * A - 8.0f * (float)p)) * 0.5f);
    if (bi < 0) bi = 0;
    while (mrowstart(bi + 1) <= p) ++bi;
    while (mrowstart(bi) > p) --bi;
    int bj = bi + (int)(p - mrowstart(bi));
    unsigned i0 = (unsigned)bi * MT, j0 = (unsigned)bj * MT;

    int tc4 = (threadIdx.x & 15) * 4;   // column sub-block
    int tr4 = (threadIdx.x >> 4) * 4;   // row sub-block

    if (bi != bj) {
        float v[4][4];
        #pragma unroll
        for (int q = 0; q < 4; ++q) {
            unsigned i = i0 + (unsigned)(tr4 + q);
            unsigned idx = triidx(i, j0 + (unsigned)tc4);
            #pragma unroll
            for (int d = 0; d < 4; ++d) v[q][d] = w[idx + (unsigned)d];
        }
        // direct block: rows i0+tr4.., cols j0+tc4..
        #pragma unroll
        for (int q = 0; q < 4; ++q) {
            ushort4 h;
            h.x = __half_as_ushort(__float2half_rn(v[q][0]));
            h.y = __half_as_ushort(__float2half_rn(v[q][1]));
            h.z = __half_as_ushort(__float2half_rn(v[q][2]));
            h.w = __half_as_ushort(__float2half_rn(v[q][3]));
            *(ushort4*)&M[(size_t)(i0 + tr4 + q) * T + j0 + tc4] = h;
        }
        // transposed block: rows j0+tc4.., cols i0+tr4..
        #pragma unroll
        for (int d = 0; d < 4; ++d) {
            ushort4 h;
            h.x = __half_as_ushort(__float2half_rn(v[0][d]));
            h.y = __half_as_ushort(__float2half_rn(v[1][d]));
            h.z = __half_as_ushort(__float2half_rn(v[2][d]));
            h.w = __half_as_ushort(__float2half_rn(v[3][d]));
            *(ushort4*)&M[(size_t)(j0 + tc4 + d) * T + i0 + tr4] = h;
        }
    } else {
        // diagonal tile: elementwise with mirroring, diag = 0
        #pragma unroll
        for (int q = 0; q < 4; ++q) {
            int rr = tr4 + q;
            ushort hv[4];
            #pragma unroll
            for (int d = 0; d < 4; ++d) {
                int cc = tc4 + d;
                float val = 0.0f;
                if (cc > rr)      val = w[triidx(i0 + (unsigned)rr, i0 + (unsigned)cc)];
                else if (cc < rr) val = w[triidx(i0 + (unsigned)cc, i0 + (unsigned)rr)];
                hv[d] = __half_as_ushort(__float2half_rn(val));
            }
            ushort4 h; h.x = hv[0]; h.y = hv[1]; h.z = hv[2]; h.w = hv[3];
            *(ushort4*)&M[(size_t)(i0 + rr) * T + i0 + tc4] = h;
        }
    }
}

__global__ __launch_bounds__(256) void init_kernel(const float* __restrict__ in,
                                                   __half* __restrict__ s) {
    int n = blockIdx.x * 256 + threadIdx.x;
    if (n < T) s[n] = __float2half_rn((n < IN) ? in[n] : 0.0f);
}

// Fused y = M s ; out = tanh(y + b). One wave per row, 4 rows/block.
__global__ __launch_bounds__(256) void gemv_kernel(
    const __half* __restrict__ M, const __half* __restrict__ sin,
    const float* __restrict__ b, __half* __restrict__ sout,
    float* __restrict__ fout, int row0, int ncol)
{
    __shared__ __align__(16) __half ss[T];   // 16 KB state stage
    int t = threadIdx.x;
    int nv = ncol >> 3;                      // uint4 chunks
    for (int k = t; k < nv; k += 256)
        ((uint4*)ss)[k] = ((const uint4*)sin)[k];
    __syncthreads();

    int wv = t >> 6, lane = t & 63;
    int row = row0 + (int)blockIdx.x * 4 + wv;
    const __half* mr = M + (size_t)row * T;

    float acc0 = 0.0f, acc1 = 0.0f;
    int niter = ncol >> 9;                   // 512 cols per iter
    #pragma unroll 4
    for (int k = 0; k < niter; ++k) {
        int col = (k << 9) + lane * 8;
        uint4 mv = *(const uint4*)(mr + col);
        uint4 sv = *(const uint4*)(ss + col);
        float2 a0 = __half22float2(*reinterpret_cast<__half2*>(&mv.x));
        float2 a1 = __half22float2(*reinterpret_cast<__half2*>(&mv.y));
        float2 a2 = __half22float2(*reinterpret_cast<__half2*>(&mv.z));
        float2 a3 = __half22float2(*reinterpret_cast<__half2*>(&mv.w));
        float2 s0 = __half22float2(*reinterpret_cast<__half2*>(&sv.x));
        float2 s1 = __half22float2(*reinterpret_cast<__half2*>(&sv.y));
        float2 s2 = __half22float2(*reinterpret_cast<__half2*>(&sv.z));
        float2 s3 = __half22float2(*reinterpret_cast<__half2*>(&sv.w));
        acc0 = fmaf(a0.x, s0.x, acc0); acc0 = fmaf(a0.y, s0.y, acc0);
        acc0 = fmaf(a1.x, s1.x, acc0); acc0 = fmaf(a1.y, s1.y, acc0);
        acc1 = fmaf(a2.x, s2.x, acc1); acc1 = fmaf(a2.y, s2.y, acc1);
        acc1 = fmaf(a3.x, s3.x, acc1); acc1 = fmaf(a3.y, s3.y, acc1);
    }
    float acc = acc0 + acc1;
    #pragma unroll
    for (int o = 32; o; o >>= 1) acc += __shfl_xor(acc, o, 64);
    if (lane == 0) {
        float yv = tanhf(acc + b[row]);
        if (fout) fout[row - row0] = yv;
        else      sout[row] = __float2half_rn(yv);
    }
}

extern "C" void kernel_launch(void* const* d_in, const int* in_sizes, int n_in,
                              void* d_out, int out_size, void* d_ws, size_t ws_size,
                              hipStream_t stream) {
    const float* in = (const float*)d_in[0];   // inputs [2048]
    const float* w  = (const float*)d_in[1];   // w_flat [T*(T-1)/2] f32
    const float* b  = (const float*)d_in[2];   // b [8192] f32
    float* out = (float*)d_out;                // [1024] f32

    __half* M  = (__half*)d_ws;                        // 128 MiB
    __half* s0 = (__half*)((char*)d_ws + (size_t)T * T * sizeof(__half));
    __half* s1 = s0 + T;

    mat_kernel<<<MNTILES, 256, 0, stream>>>(w, M);
    init_kernel<<<T / 256, 256, 0, stream>>>(in, s0);

    __half* cur = s0;
    __half* nxt = s1;
    // iter 1: state is zero past IN -> only read M[:, :IN]
    gemv_kernel<<<T / 4, 256, 0, stream>>>(M, cur, b, nxt, nullptr, 0, IN);
    { __half* tmp = cur; cur = nxt; nxt = tmp; }
    // iters 2..7: full GEMV
    for (int it = 1; it < NPROP - 1; ++it) {
        gemv_kernel<<<T / 4, 256, 0, stream>>>(M, cur, b, nxt, nullptr, 0, T);
        __half* tmp = cur; cur = nxt; nxt = tmp;
    }
    // iter 8: only the last OUT rows are returned; write f32 directly
    gemv_kernel<<<OUT / 4, 256, 0, stream>>>(M, cur, b, nullptr, out, T - OUT, T);
}